// Round 2
// baseline (214.553 us; speedup 1.0000x reference)
//
#include <hip/hip_runtime.h>

typedef __bf16 bf16;
typedef __bf16 bf16x8 __attribute__((ext_vector_type(8)));
typedef __bf16 bf16x4 __attribute__((ext_vector_type(4)));
typedef float  f32x4  __attribute__((ext_vector_type(4)));

#define MFMA_BF16(a, b, c) __builtin_amdgcn_mfma_f32_16x16x32_bf16((a), (b), (c), 0, 0, 0)

// Problem constants: B=2, L=2048, E=1024, H=16, D=64; M=B*L=4096, K=N=E=1024.

__device__ __forceinline__ void async_load16(const bf16* g, const bf16* l) {
    auto gp = (const __attribute__((address_space(1))) unsigned int*)(unsigned long long)(const void*)g;
    auto lp = (__attribute__((address_space(3))) unsigned int*)(unsigned int)(unsigned long long)(const void*)l;
    __builtin_amdgcn_global_load_lds(gp, lp, 16, 0, 0);
}

// ---------------------------------------------------------------------------
// fp32 -> bf16 conversion. Flat 1D grid (16384 blocks), 4 elems/thread.
// Layout: 3 activations of 2^22 elems, then 4 weights of 2^20 elems.
__global__ void cvt_bf16_kernel(
    const float* __restrict__ s0, const float* __restrict__ s1, const float* __restrict__ s2,
    const float* __restrict__ s3, const float* __restrict__ s4, const float* __restrict__ s5,
    const float* __restrict__ s6,
    bf16* __restrict__ d0, bf16* __restrict__ d1, bf16* __restrict__ d2,
    bf16* __restrict__ d3, bf16* __restrict__ d4, bf16* __restrict__ d5,
    bf16* __restrict__ d6)
{
    unsigned e = (blockIdx.x * 256 + threadIdx.x) * 4;
    const float* src; bf16* dst; unsigned off;
    if (e < 12582912u) {
        unsigned which = e >> 22;
        src = which == 0 ? s0 : (which == 1 ? s1 : s2);
        dst = which == 0 ? d0 : (which == 1 ? d1 : d2);
        off = e & 4194303u;
    } else {
        unsigned ew = e - 12582912u;
        unsigned which = ew >> 20;
        src = which == 0 ? s3 : (which == 1 ? s4 : (which == 2 ? s5 : s6));
        dst = which == 0 ? d3 : (which == 1 ? d4 : (which == 2 ? d5 : d6));
        off = ew & 1048575u;
    }
    float4 f = *(const float4*)(src + off);
    bf16x4 o;
    o.x = (bf16)f.x; o.y = (bf16)f.y; o.z = (bf16)f.z; o.w = (bf16)f.w;
    *(bf16x4*)(dst + off) = o;
}

// ---------------------------------------------------------------------------
// Tiled bf16 GEMM, BM=128 x BN (template), BK=32, 4 waves (2x2).
// Orientation chosen per output so the 4 r-values (C/D rows) are
// address-consecutive in the destination -> all stores bf16x4/float4:
//  z=0 (A=Wq, B=Xq): +bq, *0.125*log2e -> Qs [B,H,L,D]
//  z=1 (A=Wk, B=Xk): -> Ksw fragment-major (d lands on j)
//  z=2 (A=Xv, B=Wv): -> Vsw fragment-major (token lands on j)
//  z=3 (A=Wo, B=attn): +bo -> out fp32 (feature-contiguous float4)
template<int BN>
__global__ __launch_bounds__(256, (BN == 128) ? 2 : 4) void gemm4_kernel(
    const bf16* __restrict__ Xq, const bf16* __restrict__ Xk, const bf16* __restrict__ Xv,
    const bf16* __restrict__ Ao,
    const bf16* __restrict__ Wq, const bf16* __restrict__ Wk, const bf16* __restrict__ Wv,
    const bf16* __restrict__ Wo,
    const float* __restrict__ bq, const float* __restrict__ bo,
    bf16* __restrict__ Qs, bf16* __restrict__ Ksw, bf16* __restrict__ Vsw,
    float* __restrict__ out, int zbase)
{
    const int z = zbase + blockIdx.z;
    const bf16 *Amat, *Bmat;
    if (z == 0)      { Amat = Wq; Bmat = Xq; }
    else if (z == 1) { Amat = Wk; Bmat = Xk; }
    else if (z == 2) { Amat = Xv; Bmat = Wv; }
    else             { Amat = Wo; Bmat = Ao; }

    const int m0 = (z == 2 ? blockIdx.y : blockIdx.x) * 128;
    const int n0 = (z == 2 ? blockIdx.x : blockIdx.y) * BN;

    __shared__ __align__(16) bf16 lA[128 * 32];
    __shared__ __align__(16) bf16 lB[BN * 32];

    const int tid  = threadIdx.x;
    const int w    = tid >> 6;
    const int lane = tid & 63;
    const int lm   = lane & 15;
    const int g    = lane >> 4;
    const int wm   = (w & 1) * 64;
    const int wn   = (w >> 1) * (BN / 2);
    constexpr int NT = BN / 32;
    constexpr int T  = (128 + BN) / 64;

    f32x4 acc[4][NT] = {};

    for (int kb = 0; kb < 32; kb++) {
        __syncthreads();
#pragma unroll
        for (int t = 0; t < T; t++) {
            int s   = (t * 4 + w) * 64 + lane;
            int row = s >> 2;
            int gs  = s & 3;
            int gg  = gs ^ ((row >> 1) & 3);
            if (row < 128)
                async_load16(Amat + (size_t)(m0 + row) * 1024 + kb * 32 + gg * 8, lA + s * 8);
            else
                async_load16(Bmat + (size_t)(n0 + row - 128) * 1024 + kb * 32 + gg * 8,
                             lB + (s - 512) * 8);
        }
        __syncthreads();

        bf16x8 af[4], bfr[NT];
#pragma unroll
        for (int mt = 0; mt < 4; mt++) {
            int row = wm + mt * 16 + lm;
            af[mt] = *(const bf16x8*)(lA + row * 32 + ((g ^ ((row >> 1) & 3)) << 3));
        }
#pragma unroll
        for (int nt = 0; nt < NT; nt++) {
            int row = wn + nt * 16 + lm;
            bfr[nt] = *(const bf16x8*)(lB + row * 32 + ((g ^ ((row >> 1) & 3)) << 3));
        }
#pragma unroll
        for (int mt = 0; mt < 4; mt++)
#pragma unroll
            for (int nt = 0; nt < NT; nt++)
                acc[mt][nt] = MFMA_BF16(af[mt], bfr[nt], acc[mt][nt]);
    }

    if (z == 3) {
#pragma unroll
        for (int mt = 0; mt < 4; mt++) {
            int mb = m0 + wm + mt * 16 + g * 4;
            f32x4 bov = *(const f32x4*)(bo + mb);
#pragma unroll
            for (int nt = 0; nt < NT; nt++) {
                int n = n0 + wn + nt * 16 + lm;
                f32x4 val;
#pragma unroll
                for (int r = 0; r < 4; r++) val[r] = acc[mt][nt][r] + bov[r];
                *(f32x4*)(out + (size_t)n * 1024 + mb) = val;
            }
        }
    } else if (z == 2) {
#pragma unroll
        for (int mt = 0; mt < 4; mt++) {
            int mb   = m0 + wm + mt * 16 + g * 4;
            int b    = mb >> 11;
            int lpos = mb & 2047;
            int kb2  = lpos >> 6, kc = (lpos >> 5) & 1, gv = (lpos >> 3) & 3, j0 = lpos & 7;
#pragma unroll
            for (int nt = 0; nt < NT; nt++) {
                int n = n0 + wn + nt * 16 + lm;
                int h = n >> 6, mt2 = (n >> 4) & 3, lmv = n & 15;
                bf16x4 ov;
#pragma unroll
                for (int r = 0; r < 4; r++) ov[r] = (bf16)acc[mt][nt][r];
                *(bf16x4*)(Vsw + (size_t)(b * 16 + h) * 131072 +
                           (size_t)((kb2 * 8 + mt2 * 2 + kc) * 64 + gv * 16 + lmv) * 8 + j0) = ov;
            }
        }
    } else if (z == 1) {
#pragma unroll
        for (int mt = 0; mt < 4; mt++) {
            int mb = m0 + wm + mt * 16 + g * 4;
            int h  = mb >> 6;
            int f  = (mb >> 5) & 1, gk = (mb >> 3) & 3, j0 = mb & 7;
#pragma unroll
            for (int nt = 0; nt < NT; nt++) {
                int n    = n0 + wn + nt * 16 + lm;
                int b    = n >> 11;
                int lpos = n & 2047;
                int kb2  = lpos >> 6;
                int rem  = lpos & 63;
                int c    = ((rem >> 4) & 2) | ((rem >> 2) & 1);
                int lmk  = ((rem >> 1) & 12) | (rem & 3);
                bf16x4 ov;
#pragma unroll
                for (int r = 0; r < 4; r++) ov[r] = (bf16)acc[mt][nt][r];
                *(bf16x4*)(Ksw + (size_t)(b * 16 + h) * 131072 +
                           (size_t)((kb2 * 8 + c * 2 + f) * 64 + gk * 16 + lmk) * 8 + j0) = ov;
            }
        }
    } else {
        const float qscale = 0.18033688011112042f;  // 1/8 * log2(e)
#pragma unroll
        for (int mt = 0; mt < 4; mt++) {
            int mb  = m0 + wm + mt * 16 + g * 4;
            int h   = mb >> 6;
            int dd0 = mb & 63;
            f32x4 bqv = *(const f32x4*)(bq + mb);
#pragma unroll
            for (int nt = 0; nt < NT; nt++) {
                int n    = n0 + wn + nt * 16 + lm;
                int b    = n >> 11;
                int lpos = n & 2047;
                bf16x4 ov;
#pragma unroll
                for (int r = 0; r < 4; r++)
                    ov[r] = (bf16)((acc[mt][nt][r] + bqv[r]) * qscale);
                *(bf16x4*)(Qs + (size_t)((b * 16 + h) * 2048 + lpos) * 64 + dd0) = ov;
            }
        }
    }
}

// ---------------------------------------------------------------------------
// Flash attention v5: NO LDS staging, NO in-loop barriers. K/V per head is
// 512 KB; with 4 heads per XCD (bh swizzle) the working set is 2 MB -- L2-
// resident. The fragment-major K/V layout makes every MFMA operand a single
// coalesced per-lane bf16x8 global load (64 x 16B = 1 KB/instruction), so we
// read fragments straight from L2/L1 and let the 8 free-running waves/CU
// hide the latency (no lockstep vmcnt(0) drain -- that drain was ~2/3 of
// kernel time in the staged version: 3520 cyc/iter/SIMD vs ~1200 of pipe
// work). Software pipeline at zero register cost: kf reloaded for stripe
// kb+1 right after QK^T consumes it (hides under softmax+PV), vf reloaded
// right after PV (hides under next QK^T). s_setprio(1) around MFMA clusters
// (free-running waves = role diversity, the regime where T5 pays).
__global__ __launch_bounds__(256, 2) void attn_kernel(
    const bf16* __restrict__ Qs, const bf16* __restrict__ Ksw,
    const bf16* __restrict__ Vsw, bf16* __restrict__ attn)
{
    const int tid  = threadIdx.x;
    const int w    = tid >> 6;
    const int lane = tid & 63;
    const int lm   = lane & 15;
    const int g    = lane >> 4;
    const int i    = blockIdx.x;
    const int bh   = ((i & 7) << 2) | ((i >> 3) & 3);  // 4 heads per XCD
    const int q0   = (i >> 5) * 128 + w * 32;

    const bf16* Qh = Qs  + (size_t)bh * 131072;
    const bf16* Kh = Ksw + (size_t)bh * 131072;
    const bf16* Vh = Vsw + (size_t)bh * 131072;

    __shared__ __align__(16) bf16 ost[4][32 * 72];

    // Q fragments (B operand): lane lm = q, k(=d) = f*32 + g*8 + j
    bf16x8 qf[2][2];
#pragma unroll
    for (int qi = 0; qi < 2; qi++)
#pragma unroll
        for (int f = 0; f < 2; f++)
            qf[qi][f] = *(const bf16x8*)(Qh + (size_t)(q0 + qi * 16 + lm) * 64 + f * 32 + g * 8);

    const f32x4 fzero = {0.0f, 0.0f, 0.0f, 0.0f};
    f32x4 o[2][4] = {};
    float lsum[2] = {0.0f, 0.0f};

    // prologue: stripe-0 fragments into registers
    bf16x8 kf[8], vf[8];
#pragma unroll
    for (int t = 0; t < 8; t++)
        kf[t] = *(const bf16x8*)(Kh + ((size_t)t * 64 + lane) * 8);
#pragma unroll
    for (int t = 0; t < 8; t++)
        vf[t] = *(const bf16x8*)(Vh + ((size_t)t * 64 + lane) * 8);

    for (int kb = 0; kb < 32; kb++) {
        // next-stripe base (clamped: last iteration re-reads stripe 31, unused)
        const int kn = (kb < 31) ? kb + 1 : 31;
        const bf16* Kn = Kh + (size_t)kn * 4096;
        const bf16* Vn = Vh + (size_t)kn * 4096;

        // S^T: s[qi][c][r] = S at k = 32*(c>>1) + 8g + 4*(c&1) + r
        f32x4 s[2][4];
        __builtin_amdgcn_s_setprio(1);
#pragma unroll
        for (int c = 0; c < 4; c++) {
            s[0][c] = MFMA_BF16(kf[2 * c],     qf[0][0], fzero);
            s[1][c] = MFMA_BF16(kf[2 * c],     qf[1][0], fzero);
            s[0][c] = MFMA_BF16(kf[2 * c + 1], qf[0][1], s[0][c]);
            s[1][c] = MFMA_BF16(kf[2 * c + 1], qf[1][1], s[1][c]);
        }
        __builtin_amdgcn_s_setprio(0);

        // reload kf with stripe kb+1 -- latency hides under softmax + PV
#pragma unroll
        for (int t = 0; t < 8; t++)
            kf[t] = *(const bf16x8*)(Kn + ((size_t)t * 64 + lane) * 8);

        // p = exp2(s) -> PV B-fragments (k = 32*kc + 8g + j); VALU denominator
        bf16x8 pb[2][2];
#pragma unroll
        for (int qi = 0; qi < 2; qi++) {
            float part = 0.0f;
#pragma unroll
            for (int kc = 0; kc < 2; kc++)
#pragma unroll
                for (int r = 0; r < 4; r++) {
                    float p0 = __builtin_amdgcn_exp2f(s[qi][2 * kc][r]);
                    float p1 = __builtin_amdgcn_exp2f(s[qi][2 * kc + 1][r]);
                    pb[qi][kc][r]     = (bf16)p0;
                    pb[qi][kc][r + 4] = (bf16)p1;
                    part += p0 + p1;
                }
            lsum[qi] += part;
        }

        // O^T += V^T P
        __builtin_amdgcn_s_setprio(1);
#pragma unroll
        for (int kc = 0; kc < 2; kc++)
#pragma unroll
            for (int mt = 0; mt < 4; mt++) {
                o[0][mt] = MFMA_BF16(vf[mt * 2 + kc], pb[0][kc], o[0][mt]);
                o[1][mt] = MFMA_BF16(vf[mt * 2 + kc], pb[1][kc], o[1][mt]);
            }
        __builtin_amdgcn_s_setprio(0);

        // reload vf with stripe kb+1 -- latency hides under next QK^T + softmax
#pragma unroll
        for (int t = 0; t < 8; t++)
            vf[t] = *(const bf16x8*)(Vn + ((size_t)t * 64 + lane) * 8);
    }

    // finish denominator: k lives on (in-lane, quad); reduce across quads
#pragma unroll
    for (int qi = 0; qi < 2; qi++) {
        lsum[qi] += __shfl_xor(lsum[qi], 16);
        lsum[qi] += __shfl_xor(lsum[qi], 32);
    }

    // normalized O -> per-wave LDS region (stride 72), then 16B/lane stores
    const int b = bh >> 4, h = bh & 15;
#pragma unroll
    for (int qi = 0; qi < 2; qi++) {
        float inv = 1.0f / lsum[qi];
#pragma unroll
        for (int mt = 0; mt < 4; mt++) {
            bf16x4 ov;
#pragma unroll
            for (int r = 0; r < 4; r++) ov[r] = (bf16)(o[qi][mt][r] * inv);
            *(bf16x4*)(ost[w] + (qi * 16 + lm) * 72 + mt * 16 + g * 4) = ov;
        }
    }
#pragma unroll
    for (int it = 0; it < 4; it++) {
        int cc = it * 64 + lane;
        int q  = cc >> 3, ch = cc & 7;
        bf16x8 t = *(const bf16x8*)(ost[w] + q * 72 + ch * 8);
        *(bf16x8*)(attn + (size_t)(b * 2048 + q0 + q) * 1024 + h * 64 + ch * 8) = t;
    }
}

// ---------------------------------------------------------------------------
extern "C" void kernel_launch(void* const* d_in, const int* in_sizes, int n_in,
                              void* d_out, int out_size, void* d_ws, size_t ws_size,
                              hipStream_t stream) {
    const float* query = (const float*)d_in[0];
    const float* key   = (const float*)d_in[1];
    const float* value = (const float*)d_in[2];
    const float* Wq    = (const float*)d_in[3];
    const float* bq    = (const float*)d_in[4];
    const float* Wk    = (const float*)d_in[5];
    const float* Wv    = (const float*)d_in[6];
    const float* Wo    = (const float*)d_in[7];
    const float* bo    = (const float*)d_in[8];

    char* ws = (char*)d_ws;
    bf16* Xq  = (bf16*)(ws);
    bf16* Xk  = (bf16*)(ws + ((size_t)8  << 20));
    bf16* Xv  = (bf16*)(ws + ((size_t)16 << 20));
    bf16* Wqb = (bf16*)(ws + ((size_t)24 << 20));
    bf16* Wkb = (bf16*)(ws + ((size_t)26 << 20));
    bf16* Wvb = (bf16*)(ws + ((size_t)28 << 20));
    bf16* Wob = (bf16*)(ws + ((size_t)30 << 20));
    bf16* Qs  = (bf16*)(ws + ((size_t)32 << 20));
    bf16* Ksw = (bf16*)(ws + ((size_t)40 << 20));
    bf16* Vsw = (bf16*)(ws + ((size_t)48 << 20));
    bf16* attn = Xq;  // Xq dead after projections

    cvt_bf16_kernel<<<dim3(16384, 1, 1), 256, 0, stream>>>(
        query, key, value, Wq, Wk, Wv, Wo, Xq, Xk, Xv, Wqb, Wkb, Wvb, Wob);

    gemm4_kernel<128><<<dim3(8, 32, 3), 256, 0, stream>>>(
        Xq, Xk, Xv, attn, Wqb, Wkb, Wvb, Wob, bq, bo, Qs, Ksw, Vsw, (float*)d_out, 0);

    attn_kernel<<<dim3(512, 1, 1), 256, 0, stream>>>(Qs, Ksw, Vsw, attn);

    gemm4_kernel<64><<<dim3(8, 64, 1), 256, 0, stream>>>(
        Xq, Xk, Xv, attn, Wqb, Wkb, Wvb, Wob, bq, bo, Qs, Ksw, Vsw, (float*)d_out, 3);
}

// Round 3
// 206.280 us; speedup vs baseline: 1.0401x; 1.0401x over previous
//
#include <hip/hip_runtime.h>

typedef __bf16 bf16;
typedef __bf16 bf16x8 __attribute__((ext_vector_type(8)));
typedef __bf16 bf16x4 __attribute__((ext_vector_type(4)));
typedef float  f32x4  __attribute__((ext_vector_type(4)));

#define MFMA_BF16(a, b, c) __builtin_amdgcn_mfma_f32_16x16x32_bf16((a), (b), (c), 0, 0, 0)

// Problem constants: B=2, L=2048, E=1024, H=16, D=64; M=B*L=4096, K=N=E=1024.

__device__ __forceinline__ void async_load16(const bf16* g, const bf16* l) {
    auto gp = (const __attribute__((address_space(1))) unsigned int*)(unsigned long long)(const void*)g;
    auto lp = (__attribute__((address_space(3))) unsigned int*)(unsigned int)(unsigned long long)(const void*)l;
    __builtin_amdgcn_global_load_lds(gp, lp, 16, 0, 0);
}

// ---------------------------------------------------------------------------
// fp32 -> bf16 conversion. Flat 1D grid (16384 blocks), 4 elems/thread.
// Layout: 3 activations of 2^22 elems, then 4 weights of 2^20 elems.
__global__ void cvt_bf16_kernel(
    const float* __restrict__ s0, const float* __restrict__ s1, const float* __restrict__ s2,
    const float* __restrict__ s3, const float* __restrict__ s4, const float* __restrict__ s5,
    const float* __restrict__ s6,
    bf16* __restrict__ d0, bf16* __restrict__ d1, bf16* __restrict__ d2,
    bf16* __restrict__ d3, bf16* __restrict__ d4, bf16* __restrict__ d5,
    bf16* __restrict__ d6)
{
    unsigned e = (blockIdx.x * 256 + threadIdx.x) * 4;
    const float* src; bf16* dst; unsigned off;
    if (e < 12582912u) {
        unsigned which = e >> 22;
        src = which == 0 ? s0 : (which == 1 ? s1 : s2);
        dst = which == 0 ? d0 : (which == 1 ? d1 : d2);
        off = e & 4194303u;
    } else {
        unsigned ew = e - 12582912u;
        unsigned which = ew >> 20;
        src = which == 0 ? s3 : (which == 1 ? s4 : (which == 2 ? s5 : s6));
        dst = which == 0 ? d3 : (which == 1 ? d4 : (which == 2 ? d5 : d6));
        off = ew & 1048575u;
    }
    float4 f = *(const float4*)(src + off);
    bf16x4 o;
    o.x = (bf16)f.x; o.y = (bf16)f.y; o.z = (bf16)f.z; o.w = (bf16)f.w;
    *(bf16x4*)(dst + off) = o;
}

// ---------------------------------------------------------------------------
// Tiled bf16 GEMM, BM=128 x BN (template), BK=32 x 2 stripes/barrier,
// 4 waves (2x2).
//
// XCD-aware tile remap (T1): HW assigns xcd = blockid % 8, and blockid =
// blockIdx.x + 8*blockIdx.y, so without remap each XCD got ONE feature-tile
// x ALL token-tiles -> zero B-panel reuse inside an XCD L2 (measured 101 MB
// FETCH vs ~30 MB ideal, every staging drain eating an L2-miss latency).
// Remap: c = flat&7 (the XCD), j = flat>>3; feature_tile = j&7,
// token_tile = c*(gy/8) + (j>>3). Each XCD now owns a contiguous token-tile
// chunk x all 8 feature tiles: working set = weights 2 MB + tokens 1 MB
// < 4 MB per-XCD L2.
//
// Two BK=32 stripes are staged per barrier pair (LDS 32 KB for BN=128):
// halves the number of lockstep vmcnt(0) drains (32 -> 16), doubling the
// MFMA work amortizing each drain.
//
// Orientation per output so the 4 r-values (C/D rows) are address-consecutive
// in the destination -> all stores bf16x4/float4:
//  z=0 (A=Wq, B=Xq): +bq, *0.125*log2e -> Qs [B,H,L,D]
//  z=1 (A=Wk, B=Xk): -> Ksw fragment-major (d lands on j)
//  z=2 (A=Xv, B=Wv): -> Vsw fragment-major (token lands on j)
//  z=3 (A=Wo, B=attn): +bo -> out fp32 (feature-contiguous float4)
template<int BN>
__global__ __launch_bounds__(256, (BN == 128) ? 2 : 4) void gemm4_kernel(
    const bf16* __restrict__ Xq, const bf16* __restrict__ Xk, const bf16* __restrict__ Xv,
    const bf16* __restrict__ Ao,
    const bf16* __restrict__ Wq, const bf16* __restrict__ Wk, const bf16* __restrict__ Wv,
    const bf16* __restrict__ Wo,
    const float* __restrict__ bq, const float* __restrict__ bo,
    bf16* __restrict__ Qs, bf16* __restrict__ Ksw, bf16* __restrict__ Vsw,
    float* __restrict__ out, int zbase)
{
    const int z = zbase + blockIdx.z;
    const bf16 *Amat, *Bmat;
    if (z == 0)      { Amat = Wq; Bmat = Xq; }
    else if (z == 1) { Amat = Wk; Bmat = Xk; }
    else if (z == 2) { Amat = Xv; Bmat = Wv; }
    else             { Amat = Wo; Bmat = Ao; }

    // XCD-aware remap (bijective: gy is a multiple of 8 for both launches)
    const int flat = blockIdx.x + 8 * blockIdx.y;
    const int c    = flat & 7;           // XCD (blockid % 8)
    const int j    = flat >> 3;          // position within this XCD's chunk
    const int ft   = j & 7;              // feature tile (8 x 128)
    const int tt   = c * (gridDim.y >> 3) + (j >> 3);  // token tile

    const int m0 = (z == 2 ? tt : ft) * 128;
    const int n0 = (z == 2 ? ft : tt) * BN;

    __shared__ __align__(16) bf16 lA[2][128 * 32];
    __shared__ __align__(16) bf16 lB[2][BN * 32];

    const int tid  = threadIdx.x;
    const int w    = tid >> 6;
    const int lane = tid & 63;
    const int lm   = lane & 15;
    const int g    = lane >> 4;
    const int wm   = (w & 1) * 64;
    const int wn   = (w >> 1) * (BN / 2);
    constexpr int NT = BN / 32;
    constexpr int T  = (128 + BN) / 64;

    f32x4 acc[4][NT] = {};

    for (int kb2 = 0; kb2 < 16; kb2++) {
        __syncthreads();
#pragma unroll
        for (int st = 0; st < 2; st++) {
            int kb = kb2 * 2 + st;
#pragma unroll
            for (int t = 0; t < T; t++) {
                int s   = (t * 4 + w) * 64 + lane;
                int row = s >> 2;
                int gs  = s & 3;
                int gg  = gs ^ ((row >> 1) & 3);
                if (row < 128)
                    async_load16(Amat + (size_t)(m0 + row) * 1024 + kb * 32 + gg * 8,
                                 lA[st] + s * 8);
                else
                    async_load16(Bmat + (size_t)(n0 + row - 128) * 1024 + kb * 32 + gg * 8,
                                 lB[st] + (s - 512) * 8);
            }
        }
        __syncthreads();

#pragma unroll
        for (int st = 0; st < 2; st++) {
            bf16x8 af[4], bfr[NT];
#pragma unroll
            for (int mt = 0; mt < 4; mt++) {
                int row = wm + mt * 16 + lm;
                af[mt] = *(const bf16x8*)(lA[st] + row * 32 + ((g ^ ((row >> 1) & 3)) << 3));
            }
#pragma unroll
            for (int nt = 0; nt < NT; nt++) {
                int row = wn + nt * 16 + lm;
                bfr[nt] = *(const bf16x8*)(lB[st] + row * 32 + ((g ^ ((row >> 1) & 3)) << 3));
            }
#pragma unroll
            for (int mt = 0; mt < 4; mt++)
#pragma unroll
                for (int nt = 0; nt < NT; nt++)
                    acc[mt][nt] = MFMA_BF16(af[mt], bfr[nt], acc[mt][nt]);
        }
    }

    if (z == 3) {
#pragma unroll
        for (int mt = 0; mt < 4; mt++) {
            int mb = m0 + wm + mt * 16 + g * 4;
            f32x4 bov = *(const f32x4*)(bo + mb);
#pragma unroll
            for (int nt = 0; nt < NT; nt++) {
                int n = n0 + wn + nt * 16 + lm;
                f32x4 val;
#pragma unroll
                for (int r = 0; r < 4; r++) val[r] = acc[mt][nt][r] + bov[r];
                *(f32x4*)(out + (size_t)n * 1024 + mb) = val;
            }
        }
    } else if (z == 2) {
#pragma unroll
        for (int mt = 0; mt < 4; mt++) {
            int mb   = m0 + wm + mt * 16 + g * 4;
            int b    = mb >> 11;
            int lpos = mb & 2047;
            int kb2  = lpos >> 6, kc = (lpos >> 5) & 1, gv = (lpos >> 3) & 3, j0 = lpos & 7;
#pragma unroll
            for (int nt = 0; nt < NT; nt++) {
                int n = n0 + wn + nt * 16 + lm;
                int h = n >> 6, mt2 = (n >> 4) & 3, lmv = n & 15;
                bf16x4 ov;
#pragma unroll
                for (int r = 0; r < 4; r++) ov[r] = (bf16)acc[mt][nt][r];
                *(bf16x4*)(Vsw + (size_t)(b * 16 + h) * 131072 +
                           (size_t)((kb2 * 8 + mt2 * 2 + kc) * 64 + gv * 16 + lmv) * 8 + j0) = ov;
            }
        }
    } else if (z == 1) {
#pragma unroll
        for (int mt = 0; mt < 4; mt++) {
            int mb = m0 + wm + mt * 16 + g * 4;
            int h  = mb >> 6;
            int f  = (mb >> 5) & 1, gk = (mb >> 3) & 3, j0 = mb & 7;
#pragma unroll
            for (int nt = 0; nt < NT; nt++) {
                int n    = n0 + wn + nt * 16 + lm;
                int b    = n >> 11;
                int lpos = n & 2047;
                int kb2  = lpos >> 6;
                int rem  = lpos & 63;
                int cc   = ((rem >> 4) & 2) | ((rem >> 2) & 1);
                int lmk  = ((rem >> 1) & 12) | (rem & 3);
                bf16x4 ov;
#pragma unroll
                for (int r = 0; r < 4; r++) ov[r] = (bf16)acc[mt][nt][r];
                *(bf16x4*)(Ksw + (size_t)(b * 16 + h) * 131072 +
                           (size_t)((kb2 * 8 + cc * 2 + f) * 64 + gk * 16 + lmk) * 8 + j0) = ov;
            }
        }
    } else {
        const float qscale = 0.18033688011112042f;  // 1/8 * log2(e)
#pragma unroll
        for (int mt = 0; mt < 4; mt++) {
            int mb  = m0 + wm + mt * 16 + g * 4;
            int h   = mb >> 6;
            int dd0 = mb & 63;
            f32x4 bqv = *(const f32x4*)(bq + mb);
#pragma unroll
            for (int nt = 0; nt < NT; nt++) {
                int n    = n0 + wn + nt * 16 + lm;
                int b    = n >> 11;
                int lpos = n & 2047;
                bf16x4 ov;
#pragma unroll
                for (int r = 0; r < 4; r++)
                    ov[r] = (bf16)((acc[mt][nt][r] + bqv[r]) * qscale);
                *(bf16x4*)(Qs + (size_t)((b * 16 + h) * 2048 + lpos) * 64 + dd0) = ov;
            }
        }
    }
}

// ---------------------------------------------------------------------------
// Flash attention v5: NO LDS staging, NO in-loop barriers. K/V per head is
// 512 KB; with 4 heads per XCD (bh swizzle) the working set is 2 MB -- L2-
// resident. The fragment-major K/V layout makes every MFMA operand a single
// coalesced per-lane bf16x8 global load (64 x 16B = 1 KB/instruction), so we
// read fragments straight from L2/L1 and let the 8 free-running waves/CU
// hide the latency (no lockstep vmcnt(0) drain). Software pipeline at zero
// register cost: kf reloaded for stripe kb+1 right after QK^T consumes it
// (hides under softmax+PV), vf reloaded right after PV (hides under next
// QK^T). s_setprio(1) around MFMA clusters.
__global__ __launch_bounds__(256, 2) void attn_kernel(
    const bf16* __restrict__ Qs, const bf16* __restrict__ Ksw,
    const bf16* __restrict__ Vsw, bf16* __restrict__ attn)
{
    const int tid  = threadIdx.x;
    const int w    = tid >> 6;
    const int lane = tid & 63;
    const int lm   = lane & 15;
    const int g    = lane >> 4;
    const int i    = blockIdx.x;
    const int bh   = ((i & 7) << 2) | ((i >> 3) & 3);  // 4 heads per XCD
    const int q0   = (i >> 5) * 128 + w * 32;

    const bf16* Qh = Qs  + (size_t)bh * 131072;
    const bf16* Kh = Ksw + (size_t)bh * 131072;
    const bf16* Vh = Vsw + (size_t)bh * 131072;

    __shared__ __align__(16) bf16 ost[4][32 * 72];

    // Q fragments (B operand): lane lm = q, k(=d) = f*32 + g*8 + j
    bf16x8 qf[2][2];
#pragma unroll
    for (int qi = 0; qi < 2; qi++)
#pragma unroll
        for (int f = 0; f < 2; f++)
            qf[qi][f] = *(const bf16x8*)(Qh + (size_t)(q0 + qi * 16 + lm) * 64 + f * 32 + g * 8);

    const f32x4 fzero = {0.0f, 0.0f, 0.0f, 0.0f};
    f32x4 o[2][4] = {};
    float lsum[2] = {0.0f, 0.0f};

    // prologue: stripe-0 fragments into registers
    bf16x8 kf[8], vf[8];
#pragma unroll
    for (int t = 0; t < 8; t++)
        kf[t] = *(const bf16x8*)(Kh + ((size_t)t * 64 + lane) * 8);
#pragma unroll
    for (int t = 0; t < 8; t++)
        vf[t] = *(const bf16x8*)(Vh + ((size_t)t * 64 + lane) * 8);

    for (int kb = 0; kb < 32; kb++) {
        // next-stripe base (clamped: last iteration re-reads stripe 31, unused)
        const int kn = (kb < 31) ? kb + 1 : 31;
        const bf16* Kn = Kh + (size_t)kn * 4096;
        const bf16* Vn = Vh + (size_t)kn * 4096;

        // S^T: s[qi][c][r] = S at k = 32*(c>>1) + 8g + 4*(c&1) + r
        f32x4 s[2][4];
        __builtin_amdgcn_s_setprio(1);
#pragma unroll
        for (int c = 0; c < 4; c++) {
            s[0][c] = MFMA_BF16(kf[2 * c],     qf[0][0], fzero);
            s[1][c] = MFMA_BF16(kf[2 * c],     qf[1][0], fzero);
            s[0][c] = MFMA_BF16(kf[2 * c + 1], qf[0][1], s[0][c]);
            s[1][c] = MFMA_BF16(kf[2 * c + 1], qf[1][1], s[1][c]);
        }
        __builtin_amdgcn_s_setprio(0);

        // reload kf with stripe kb+1 -- latency hides under softmax + PV
#pragma unroll
        for (int t = 0; t < 8; t++)
            kf[t] = *(const bf16x8*)(Kn + ((size_t)t * 64 + lane) * 8);

        // p = exp2(s) -> PV B-fragments (k = 32*kc + 8g + j); VALU denominator
        bf16x8 pb[2][2];
#pragma unroll
        for (int qi = 0; qi < 2; qi++) {
            float part = 0.0f;
#pragma unroll
            for (int kc = 0; kc < 2; kc++)
#pragma unroll
                for (int r = 0; r < 4; r++) {
                    float p0 = __builtin_amdgcn_exp2f(s[qi][2 * kc][r]);
                    float p1 = __builtin_amdgcn_exp2f(s[qi][2 * kc + 1][r]);
                    pb[qi][kc][r]     = (bf16)p0;
                    pb[qi][kc][r + 4] = (bf16)p1;
                    part += p0 + p1;
                }
            lsum[qi] += part;
        }

        // O^T += V^T P
        __builtin_amdgcn_s_setprio(1);
#pragma unroll
        for (int kc = 0; kc < 2; kc++)
#pragma unroll
            for (int mt = 0; mt < 4; mt++) {
                o[0][mt] = MFMA_BF16(vf[mt * 2 + kc], pb[0][kc], o[0][mt]);
                o[1][mt] = MFMA_BF16(vf[mt * 2 + kc], pb[1][kc], o[1][mt]);
            }
        __builtin_amdgcn_s_setprio(0);

        // reload vf with stripe kb+1 -- latency hides under next QK^T + softmax
#pragma unroll
        for (int t = 0; t < 8; t++)
            vf[t] = *(const bf16x8*)(Vn + ((size_t)t * 64 + lane) * 8);
    }

    // finish denominator: k lives on (in-lane, quad); reduce across quads
#pragma unroll
    for (int qi = 0; qi < 2; qi++) {
        lsum[qi] += __shfl_xor(lsum[qi], 16);
        lsum[qi] += __shfl_xor(lsum[qi], 32);
    }

    // normalized O -> per-wave LDS region (stride 72), then 16B/lane stores
    const int b = bh >> 4, h = bh & 15;
#pragma unroll
    for (int qi = 0; qi < 2; qi++) {
        float inv = 1.0f / lsum[qi];
#pragma unroll
        for (int mt = 0; mt < 4; mt++) {
            bf16x4 ov;
#pragma unroll
            for (int r = 0; r < 4; r++) ov[r] = (bf16)(o[qi][mt][r] * inv);
            *(bf16x4*)(ost[w] + (qi * 16 + lm) * 72 + mt * 16 + g * 4) = ov;
        }
    }
#pragma unroll
    for (int it = 0; it < 4; it++) {
        int cc = it * 64 + lane;
        int q  = cc >> 3, ch = cc & 7;
        bf16x8 t = *(const bf16x8*)(ost[w] + q * 72 + ch * 8);
        *(bf16x8*)(attn + (size_t)(b * 2048 + q0 + q) * 1024 + h * 64 + ch * 8) = t;
    }
}

// ---------------------------------------------------------------------------
extern "C" void kernel_launch(void* const* d_in, const int* in_sizes, int n_in,
                              void* d_out, int out_size, void* d_ws, size_t ws_size,
                              hipStream_t stream) {
    const float* query = (const float*)d_in[0];
    const float* key   = (const float*)d_in[1];
    const float* value = (const float*)d_in[2];
    const float* Wq    = (const float*)d_in[3];
    const float* bq    = (const float*)d_in[4];
    const float* Wk    = (const float*)d_in[5];
    const float* Wv    = (const float*)d_in[6];
    const float* Wo    = (const float*)d_in[7];
    const float* bo    = (const float*)d_in[8];

    char* ws = (char*)d_ws;
    bf16* Xq  = (bf16*)(ws);
    bf16* Xk  = (bf16*)(ws + ((size_t)8  << 20));
    bf16* Xv  = (bf16*)(ws + ((size_t)16 << 20));
    bf16* Wqb = (bf16*)(ws + ((size_t)24 << 20));
    bf16* Wkb = (bf16*)(ws + ((size_t)26 << 20));
    bf16* Wvb = (bf16*)(ws + ((size_t)28 << 20));
    bf16* Wob = (bf16*)(ws + ((size_t)30 << 20));
    bf16* Qs  = (bf16*)(ws + ((size_t)32 << 20));
    bf16* Ksw = (bf16*)(ws + ((size_t)40 << 20));
    bf16* Vsw = (bf16*)(ws + ((size_t)48 << 20));
    bf16* attn = Xq;  // Xq dead after projections

    cvt_bf16_kernel<<<dim3(16384, 1, 1), 256, 0, stream>>>(
        query, key, value, Wq, Wk, Wv, Wo, Xq, Xk, Xv, Wqb, Wkb, Wvb, Wob);

    gemm4_kernel<128><<<dim3(8, 32, 3), 256, 0, stream>>>(
        Xq, Xk, Xv, attn, Wqb, Wkb, Wvb, Wob, bq, bo, Qs, Ksw, Vsw, (float*)d_out, 0);

    attn_kernel<<<dim3(512, 1, 1), 256, 0, stream>>>(Qs, Ksw, Vsw, attn);

    gemm4_kernel<64><<<dim3(8, 64, 1), 256, 0, stream>>>(
        Xq, Xk, Xv, attn, Wqb, Wkb, Wvb, Wob, bq, bo, Qs, Ksw, Vsw, (float*)d_out, 3);
}

// Round 4
// 205.138 us; speedup vs baseline: 1.0459x; 1.0056x over previous
//
#include <hip/hip_runtime.h>

typedef __bf16 bf16;
typedef __bf16 bf16x8 __attribute__((ext_vector_type(8)));
typedef __bf16 bf16x4 __attribute__((ext_vector_type(4)));
typedef float  f32x4  __attribute__((ext_vector_type(4)));

#define MFMA_BF16(a, b, c) __builtin_amdgcn_mfma_f32_16x16x32_bf16((a), (b), (c), 0, 0, 0)

// Problem constants: B=2, L=2048, E=1024, H=16, D=64; M=B*L=4096, K=N=E=1024.

__device__ __forceinline__ void async_load16(const bf16* g, const bf16* l) {
    auto gp = (const __attribute__((address_space(1))) unsigned int*)(unsigned long long)(const void*)g;
    auto lp = (__attribute__((address_space(3))) unsigned int*)(unsigned int)(unsigned long long)(const void*)l;
    __builtin_amdgcn_global_load_lds(gp, lp, 16, 0, 0);
}

// ---------------------------------------------------------------------------
// fp32 -> bf16 conversion. Flat 1D grid (16384 blocks), 4 elems/thread.
// Layout: 3 activations of 2^22 elems, then 4 weights of 2^20 elems.
__global__ void cvt_bf16_kernel(
    const float* __restrict__ s0, const float* __restrict__ s1, const float* __restrict__ s2,
    const float* __restrict__ s3, const float* __restrict__ s4, const float* __restrict__ s5,
    const float* __restrict__ s6,
    bf16* __restrict__ d0, bf16* __restrict__ d1, bf16* __restrict__ d2,
    bf16* __restrict__ d3, bf16* __restrict__ d4, bf16* __restrict__ d5,
    bf16* __restrict__ d6)
{
    unsigned e = (blockIdx.x * 256 + threadIdx.x) * 4;
    const float* src; bf16* dst; unsigned off;
    if (e < 12582912u) {
        unsigned which = e >> 22;
        src = which == 0 ? s0 : (which == 1 ? s1 : s2);
        dst = which == 0 ? d0 : (which == 1 ? d1 : d2);
        off = e & 4194303u;
    } else {
        unsigned ew = e - 12582912u;
        unsigned which = ew >> 20;
        src = which == 0 ? s3 : (which == 1 ? s4 : (which == 2 ? s5 : s6));
        dst = which == 0 ? d3 : (which == 1 ? d4 : (which == 2 ? d5 : d6));
        off = ew & 1048575u;
    }
    float4 f = *(const float4*)(src + off);
    bf16x4 o;
    o.x = (bf16)f.x; o.y = (bf16)f.y; o.z = (bf16)f.z; o.w = (bf16)f.w;
    *(bf16x4*)(dst + off) = o;
}

// ---------------------------------------------------------------------------
// Tiled bf16 GEMM, BM=128 x BN (template), BK=32 x 2 stripes/barrier,
// 4 waves (2x2).
//
// XCD-aware tile remap (T1): HW assigns xcd = blockid % 8, and blockid =
// blockIdx.x + 8*blockIdx.y, so without remap each XCD got ONE feature-tile
// x ALL token-tiles -> zero B-panel reuse inside an XCD L2 (measured 101 MB
// FETCH vs ~30 MB ideal). Remap: c = flat&7 (the XCD), j = flat>>3;
// feature_tile = j&7, token_tile = c*(gy/8) + (j>>3). Per-XCD working set =
// weights 2 MB + token-panels 1 MB < 4 MB L2.  [R3: gemm4<128> left top-5]
//
// Two BK=32 stripes staged per barrier pair: halves lockstep drains (32->16).
//
// Orientation per output so the 4 r-values (C/D rows) are address-consecutive
// in the destination -> all stores bf16x4/float4:
//  z=0 (A=Wq, B=Xq): +bq, *0.125*log2e -> Qs [B,H,L,D]
//  z=1 (A=Wk, B=Xk): -> Ksw fragment-major (d lands on j)
//  z=2 (A=Xv, B=Wv): -> Vsw fragment-major (token lands on j)
//  z=3 (A=Wo, B=attn): +bo -> out fp32 (feature-contiguous float4)
template<int BN>
__global__ __launch_bounds__(256, (BN == 128) ? 2 : 4) void gemm4_kernel(
    const bf16* __restrict__ Xq, const bf16* __restrict__ Xk, const bf16* __restrict__ Xv,
    const bf16* __restrict__ Ao,
    const bf16* __restrict__ Wq, const bf16* __restrict__ Wk, const bf16* __restrict__ Wv,
    const bf16* __restrict__ Wo,
    const float* __restrict__ bq, const float* __restrict__ bo,
    bf16* __restrict__ Qs, bf16* __restrict__ Ksw, bf16* __restrict__ Vsw,
    float* __restrict__ out, int zbase)
{
    const int z = zbase + blockIdx.z;
    const bf16 *Amat, *Bmat;
    if (z == 0)      { Amat = Wq; Bmat = Xq; }
    else if (z == 1) { Amat = Wk; Bmat = Xk; }
    else if (z == 2) { Amat = Xv; Bmat = Wv; }
    else             { Amat = Wo; Bmat = Ao; }

    // XCD-aware remap (bijective: gy is a multiple of 8 for both launches)
    const int flat = blockIdx.x + 8 * blockIdx.y;
    const int c    = flat & 7;           // XCD (blockid % 8)
    const int j    = flat >> 3;          // position within this XCD's chunk
    const int ft   = j & 7;              // feature tile (8 x 128)
    const int tt   = c * (gridDim.y >> 3) + (j >> 3);  // token tile

    const int m0 = (z == 2 ? tt : ft) * 128;
    const int n0 = (z == 2 ? ft : tt) * BN;

    __shared__ __align__(16) bf16 lA[2][128 * 32];
    __shared__ __align__(16) bf16 lB[2][BN * 32];

    const int tid  = threadIdx.x;
    const int w    = tid >> 6;
    const int lane = tid & 63;
    const int lm   = lane & 15;
    const int g    = lane >> 4;
    const int wm   = (w & 1) * 64;
    const int wn   = (w >> 1) * (BN / 2);
    constexpr int NT = BN / 32;
    constexpr int T  = (128 + BN) / 64;

    f32x4 acc[4][NT] = {};

    for (int kb2 = 0; kb2 < 16; kb2++) {
        __syncthreads();
#pragma unroll
        for (int st = 0; st < 2; st++) {
            int kb = kb2 * 2 + st;
#pragma unroll
            for (int t = 0; t < T; t++) {
                int s   = (t * 4 + w) * 64 + lane;
                int row = s >> 2;
                int gs  = s & 3;
                int gg  = gs ^ ((row >> 1) & 3);
                if (row < 128)
                    async_load16(Amat + (size_t)(m0 + row) * 1024 + kb * 32 + gg * 8,
                                 lA[st] + s * 8);
                else
                    async_load16(Bmat + (size_t)(n0 + row - 128) * 1024 + kb * 32 + gg * 8,
                                 lB[st] + (s - 512) * 8);
            }
        }
        __syncthreads();

#pragma unroll
        for (int st = 0; st < 2; st++) {
            bf16x8 af[4], bfr[NT];
#pragma unroll
            for (int mt = 0; mt < 4; mt++) {
                int row = wm + mt * 16 + lm;
                af[mt] = *(const bf16x8*)(lA[st] + row * 32 + ((g ^ ((row >> 1) & 3)) << 3));
            }
#pragma unroll
            for (int nt = 0; nt < NT; nt++) {
                int row = wn + nt * 16 + lm;
                bfr[nt] = *(const bf16x8*)(lB[st] + row * 32 + ((g ^ ((row >> 1) & 3)) << 3));
            }
#pragma unroll
            for (int mt = 0; mt < 4; mt++)
#pragma unroll
                for (int nt = 0; nt < NT; nt++)
                    acc[mt][nt] = MFMA_BF16(af[mt], bfr[nt], acc[mt][nt]);
        }
    }

    if (z == 3) {
#pragma unroll
        for (int mt = 0; mt < 4; mt++) {
            int mb = m0 + wm + mt * 16 + g * 4;
            f32x4 bov = *(const f32x4*)(bo + mb);
#pragma unroll
            for (int nt = 0; nt < NT; nt++) {
                int n = n0 + wn + nt * 16 + lm;
                f32x4 val;
#pragma unroll
                for (int r = 0; r < 4; r++) val[r] = acc[mt][nt][r] + bov[r];
                *(f32x4*)(out + (size_t)n * 1024 + mb) = val;
            }
        }
    } else if (z == 2) {
#pragma unroll
        for (int mt = 0; mt < 4; mt++) {
            int mb   = m0 + wm + mt * 16 + g * 4;
            int b    = mb >> 11;
            int lpos = mb & 2047;
            int kb2  = lpos >> 6, kc = (lpos >> 5) & 1, gv = (lpos >> 3) & 3, j0 = lpos & 7;
#pragma unroll
            for (int nt = 0; nt < NT; nt++) {
                int n = n0 + wn + nt * 16 + lm;
                int h = n >> 6, mt2 = (n >> 4) & 3, lmv = n & 15;
                bf16x4 ov;
#pragma unroll
                for (int r = 0; r < 4; r++) ov[r] = (bf16)acc[mt][nt][r];
                *(bf16x4*)(Vsw + (size_t)(b * 16 + h) * 131072 +
                           (size_t)((kb2 * 8 + mt2 * 2 + kc) * 64 + gv * 16 + lmv) * 8 + j0) = ov;
            }
        }
    } else if (z == 1) {
#pragma unroll
        for (int mt = 0; mt < 4; mt++) {
            int mb = m0 + wm + mt * 16 + g * 4;
            int h  = mb >> 6;
            int f  = (mb >> 5) & 1, gk = (mb >> 3) & 3, j0 = mb & 7;
#pragma unroll
            for (int nt = 0; nt < NT; nt++) {
                int n    = n0 + wn + nt * 16 + lm;
                int b    = n >> 11;
                int lpos = n & 2047;
                int kb2  = lpos >> 6;
                int rem  = lpos & 63;
                int cc   = ((rem >> 4) & 2) | ((rem >> 2) & 1);
                int lmk  = ((rem >> 1) & 12) | (rem & 3);
                bf16x4 ov;
#pragma unroll
                for (int r = 0; r < 4; r++) ov[r] = (bf16)acc[mt][nt][r];
                *(bf16x4*)(Ksw + (size_t)(b * 16 + h) * 131072 +
                           (size_t)((kb2 * 8 + cc * 2 + f) * 64 + gk * 16 + lmk) * 8 + j0) = ov;
            }
        }
    } else {
        const float qscale = 0.18033688011112042f;  // 1/8 * log2(e)
#pragma unroll
        for (int mt = 0; mt < 4; mt++) {
            int mb  = m0 + wm + mt * 16 + g * 4;
            int h   = mb >> 6;
            int dd0 = mb & 63;
            f32x4 bqv = *(const f32x4*)(bq + mb);
#pragma unroll
            for (int nt = 0; nt < NT; nt++) {
                int n    = n0 + wn + nt * 16 + lm;
                int b    = n >> 11;
                int lpos = n & 2047;
                bf16x4 ov;
#pragma unroll
                for (int r = 0; r < 4; r++)
                    ov[r] = (bf16)((acc[mt][nt][r] + bqv[r]) * qscale);
                *(bf16x4*)(Qs + (size_t)((b * 16 + h) * 2048 + lpos) * 64 + dd0) = ov;
            }
        }
    }
}

// ---------------------------------------------------------------------------
// Flash attention v6: LDS-shared K/V staging with a 3-DEEP COUNTED-vmcnt
// pipeline (T3+T4). v5 (register-direct, no barriers) showed the block's 4
// waves each load the IDENTICAL 16 KB stripe -> 1.07 GB through L2 at 72% of
// the L2 BW ceiling -> queueing latency serialized the loads (3256 cyc/iter
// vs ~660 of pipe work). v4 (LDS-shared, __syncthreads) had 1x traffic but
// paid a vmcnt(0) drain every iteration. v6 keeps the 1x traffic AND keeps
// prefetches in flight across barriers:
//   per iter: s_waitcnt vmcnt(4)   (my 4 stripe-kb loads landed; stripe-kb+1
//                                    loads stay in flight -- never drain to 0)
//             s_barrier            (everyone's stripe-kb loads landed; all
//                                    waves done computing kb-1, so the
//                                    (kb+2)%3 buffer is free)
//             issue stage(kb+2)    (4 global_load_lds per wave, 2 deep)
//             compute stripe kb from LDS
// Invariant: at iter-kb entry the wave has stripes {kb, kb+1} = 8 loads in
// flight; vmcnt(4) retires exactly stripe kb. Last iter: vmcnt(0).
__global__ __launch_bounds__(256, 2) void attn_kernel(
    const bf16* __restrict__ Qs, const bf16* __restrict__ Ksw,
    const bf16* __restrict__ Vsw, bf16* __restrict__ attn)
{
    const int tid  = threadIdx.x;
    const int w    = tid >> 6;
    const int lane = tid & 63;
    const int lm   = lane & 15;
    const int g    = lane >> 4;
    const int i    = blockIdx.x;
    const int bh   = ((i & 7) << 2) | ((i >> 3) & 3);  // 4 heads per XCD
    const int q0   = (i >> 5) * 128 + w * 32;

    const bf16* Qh = Qs  + (size_t)bh * 131072;
    const bf16* Kh = Ksw + (size_t)bh * 131072;
    const bf16* Vh = Vsw + (size_t)bh * 131072;

    __shared__ __align__(16) bf16 kbuf[3][4096];
    __shared__ __align__(16) bf16 vbuf[3][4096];
    __shared__ __align__(16) bf16 ost[4][32 * 72];

    // Q fragments (B operand): lane lm = q, k(=d) = f*32 + g*8 + j
    bf16x8 qf[2][2];
#pragma unroll
    for (int qi = 0; qi < 2; qi++)
#pragma unroll
        for (int f = 0; f < 2; f++)
            qf[qi][f] = *(const bf16x8*)(Qh + (size_t)(q0 + qi * 16 + lm) * 64 + f * 32 + g * 8);

    // stage stripe `sb` into buffer `buf`: 16 x 1KB slots, wave w does 4
#define STAGE(sb, buf)                                                          \
    do {                                                                        \
        _Pragma("unroll")                                                       \
        for (int t = 0; t < 4; t++) {                                           \
            int slot = w * 4 + t;                                               \
            if (slot < 8)                                                       \
                async_load16(Kh + ((size_t)((sb) * 8 + slot) * 64 + lane) * 8,  \
                             kbuf[buf] + (slot * 64 + lane) * 8);               \
            else                                                                \
                async_load16(Vh + ((size_t)((sb) * 8 + slot - 8) * 64 + lane) * 8, \
                             vbuf[buf] + ((slot - 8) * 64 + lane) * 8);         \
        }                                                                       \
    } while (0)

    // prologue: stripes 0 and 1 in flight
    STAGE(0, 0);
    STAGE(1, 1);

    const f32x4 fzero = {0.0f, 0.0f, 0.0f, 0.0f};
    f32x4 o[2][4] = {};
    float lsum[2] = {0.0f, 0.0f};

    int cur = 0;
    for (int kb = 0; kb < 32; kb++) {
        if (kb < 31)
            asm volatile("s_waitcnt vmcnt(4)" ::: "memory");
        else
            asm volatile("s_waitcnt vmcnt(0)" ::: "memory");
        __builtin_amdgcn_s_barrier();
        __builtin_amdgcn_sched_barrier(0);

        if (kb < 30) {
            int nb = cur + 2; if (nb >= 3) nb -= 3;
            STAGE(kb + 2, nb);
        }

        const bf16* kc_ = kbuf[cur];
        const bf16* vc_ = vbuf[cur];

        // S^T: s[qi][c][r] = S at k = 32*(c>>1) + 8g + 4*(c&1) + r
        f32x4 s[2][4];
        __builtin_amdgcn_s_setprio(1);
#pragma unroll
        for (int c = 0; c < 4; c++) {
            bf16x8 kf0 = *(const bf16x8*)(kc_ + ((c * 2 + 0) * 64 + lane) * 8);
            bf16x8 kf1 = *(const bf16x8*)(kc_ + ((c * 2 + 1) * 64 + lane) * 8);
            s[0][c] = MFMA_BF16(kf0, qf[0][0], fzero);
            s[1][c] = MFMA_BF16(kf0, qf[1][0], fzero);
            s[0][c] = MFMA_BF16(kf1, qf[0][1], s[0][c]);
            s[1][c] = MFMA_BF16(kf1, qf[1][1], s[1][c]);
        }
        __builtin_amdgcn_s_setprio(0);

        // p = exp2(s) -> PV B-fragments (k = 32*kc + 8g + j); VALU denominator
        bf16x8 pb[2][2];
#pragma unroll
        for (int qi = 0; qi < 2; qi++) {
            float part = 0.0f;
#pragma unroll
            for (int kc = 0; kc < 2; kc++)
#pragma unroll
                for (int r = 0; r < 4; r++) {
                    float p0 = __builtin_amdgcn_exp2f(s[qi][2 * kc][r]);
                    float p1 = __builtin_amdgcn_exp2f(s[qi][2 * kc + 1][r]);
                    pb[qi][kc][r]     = (bf16)p0;
                    pb[qi][kc][r + 4] = (bf16)p1;
                    part += p0 + p1;
                }
            lsum[qi] += part;
        }

        // O^T += V^T P
        __builtin_amdgcn_s_setprio(1);
#pragma unroll
        for (int kc = 0; kc < 2; kc++)
#pragma unroll
            for (int mt = 0; mt < 4; mt++) {
                bf16x8 vf = *(const bf16x8*)(vc_ + ((mt * 2 + kc) * 64 + lane) * 8);
                o[0][mt] = MFMA_BF16(vf, pb[0][kc], o[0][mt]);
                o[1][mt] = MFMA_BF16(vf, pb[1][kc], o[1][mt]);
            }
        __builtin_amdgcn_s_setprio(0);

        cur += 1; if (cur >= 3) cur -= 3;
    }
#undef STAGE

    // finish denominator: k lives on (in-lane, quad); reduce across quads
#pragma unroll
    for (int qi = 0; qi < 2; qi++) {
        lsum[qi] += __shfl_xor(lsum[qi], 16);
        lsum[qi] += __shfl_xor(lsum[qi], 32);
    }

    // normalized O -> per-wave LDS region (stride 72), then 16B/lane stores
    const int b = bh >> 4, h = bh & 15;
#pragma unroll
    for (int qi = 0; qi < 2; qi++) {
        float inv = 1.0f / lsum[qi];
#pragma unroll
        for (int mt = 0; mt < 4; mt++) {
            bf16x4 ov;
#pragma unroll
            for (int r = 0; r < 4; r++) ov[r] = (bf16)(o[qi][mt][r] * inv);
            *(bf16x4*)(ost[w] + (qi * 16 + lm) * 72 + mt * 16 + g * 4) = ov;
        }
    }
#pragma unroll
    for (int it = 0; it < 4; it++) {
        int cc = it * 64 + lane;
        int q  = cc >> 3, ch = cc & 7;
        bf16x8 t = *(const bf16x8*)(ost[w] + q * 72 + ch * 8);
        *(bf16x8*)(attn + (size_t)(b * 2048 + q0 + q) * 1024 + h * 64 + ch * 8) = t;
    }
}

// ---------------------------------------------------------------------------
extern "C" void kernel_launch(void* const* d_in, const int* in_sizes, int n_in,
                              void* d_out, int out_size, void* d_ws, size_t ws_size,
                              hipStream_t stream) {
    const float* query = (const float*)d_in[0];
    const float* key   = (const float*)d_in[1];
    const float* value = (const float*)d_in[2];
    const float* Wq    = (const float*)d_in[3];
    const float* bq    = (const float*)d_in[4];
    const float* Wk    = (const float*)d_in[5];
    const float* Wv    = (const float*)d_in[6];
    const float* Wo    = (const float*)d_in[7];
    const float* bo    = (const float*)d_in[8];

    char* ws = (char*)d_ws;
    bf16* Xq  = (bf16*)(ws);
    bf16* Xk  = (bf16*)(ws + ((size_t)8  << 20));
    bf16* Xv  = (bf16*)(ws + ((size_t)16 << 20));
    bf16* Wqb = (bf16*)(ws + ((size_t)24 << 20));
    bf16* Wkb = (bf16*)(ws + ((size_t)26 << 20));
    bf16* Wvb = (bf16*)(ws + ((size_t)28 << 20));
    bf16* Wob = (bf16*)(ws + ((size_t)30 << 20));
    bf16* Qs  = (bf16*)(ws + ((size_t)32 << 20));
    bf16* Ksw = (bf16*)(ws + ((size_t)40 << 20));
    bf16* Vsw = (bf16*)(ws + ((size_t)48 << 20));
    bf16* attn = Xq;  // Xq dead after projections

    cvt_bf16_kernel<<<dim3(16384, 1, 1), 256, 0, stream>>>(
        query, key, value, Wq, Wk, Wv, Wo, Xq, Xk, Xv, Wqb, Wkb, Wvb, Wob);

    gemm4_kernel<128><<<dim3(8, 32, 3), 256, 0, stream>>>(
        Xq, Xk, Xv, attn, Wqb, Wkb, Wvb, Wob, bq, bo, Qs, Ksw, Vsw, (float*)d_out, 0);

    attn_kernel<<<dim3(512, 1, 1), 256, 0, stream>>>(Qs, Ksw, Vsw, attn);

    gemm4_kernel<64><<<dim3(8, 64, 1), 256, 0, stream>>>(
        Xq, Xk, Xv, attn, Wqb, Wkb, Wvb, Wob, bq, bo, Qs, Ksw, Vsw, (float*)d_out, 3);
}